// Round 14
// baseline (77.984 us; speedup 1.0000x reference)
//
#include <hip/hip_runtime.h>
#include <hip/hip_bf16.h>

// out = conv9(in) @ M^T,  M = Wout @ Win
// R14: R11-redo done right — conv fused into A-staging with DEPTH-2 window
// prefetch (P/Q reg sets). U intermediate eliminated. Queue discipline:
//   step top:    {B(kt)4 old, W(kt+1)16}          -> vmcnt(16) retires B only
//   after MFMA:  {W(kt+1)16, B(kt+1)4, W(kt+2)16} -> vmcnt(20) retires W(kt+1)
// One barrier/step. gemm_m separate small launch (proven body).

typedef unsigned short u16;
typedef unsigned int u32;
typedef unsigned long long u64;
typedef __attribute__((ext_vector_type(8))) short bf16x8;
typedef __attribute__((ext_vector_type(8))) unsigned short u16x8;
typedef __attribute__((ext_vector_type(4))) float f32x4;
typedef __attribute__((ext_vector_type(2))) u32 u32x2;

typedef __attribute__((address_space(1))) const void* as1_cvp;
typedef __attribute__((address_space(3))) void* as3_vp;

#define EDIM 512
#define NROW 16384

__device__ __forceinline__ u16 f2b(float x) {
  union { float f; u32 u; } c; c.f = x;
  return (u16)((c.u + 0x7fffu + ((c.u >> 16) & 1u)) >> 16);  // RNE
}
__device__ __forceinline__ u32 cvtpk(float lo, float hi) {
  u32 r;
  asm("v_cvt_pk_bf16_f32 %0, %1, %2" : "=v"(r) : "v"(lo), "v"(hi));
  return r;
}
__device__ __forceinline__ void async_cp16(const void* g, void* l) {
  __builtin_amdgcn_global_load_lds((as1_cvp)(u64)g, (as3_vp)(u32)(u64)l, 16, 0, 0);
}

// ---------------------------------------------------------------------------
// Kernel 1: M[f,e] = sum_c Wout[f,c]*Win[c,e] (512^3). Proven R12 body.
// ---------------------------------------------------------------------------
__global__ __launch_bounds__(256) void gemm_m(const float* __restrict__ Wout,
                                              const float* __restrict__ Win,
                                              u16* __restrict__ Mm) {
  __shared__ u16 plds[17408];
  int t = threadIdx.x;
  u16* la = plds;
  u16* lbt = plds + 8704;
  int w = t >> 6, l = t & 63, lr = l & 15, lk = l >> 4;
  int f0 = ((int)blockIdx.x >> 3) * 64, e0 = ((int)blockIdx.x & 7) * 64;
  int arow = t >> 2, acol = (t & 3) * 32;
  int cq = t >> 3, eo = (t & 7) * 8;
  const float* pA = Wout + (u64)(f0 + arow) * EDIM + acol;
  const float* pB = Win + (u64)(4 * cq) * EDIM + e0 + eo;
  f32x4 a8[8], b8[8];
#pragma unroll
  for (int i = 0; i < 8; ++i) a8[i] = *(const f32x4*)(pA + i * 4);
#pragma unroll
  for (int r = 0; r < 4; ++r) {
    b8[r * 2 + 0] = *(const f32x4*)(pB + r * EDIM);
    b8[r * 2 + 1] = *(const f32x4*)(pB + r * EDIM + 4);
  }
  f32x4 acc[4] = {};
  for (int kt = 0; kt < 4; ++kt) {
#pragma unroll
    for (int i = 0; i < 4; ++i) {
      u16x8 o;
#pragma unroll
      for (int q = 0; q < 4; ++q) { o[q] = f2b(a8[2 * i][q]); o[4 + q] = f2b(a8[2 * i + 1][q]); }
      *(u16x8*)(la + arow * 136 + acol + i * 8) = o;
    }
#pragma unroll
    for (int j = 0; j < 8; ++j) {
      u32x2 p;
      p[0] = cvtpk(b8[0 + (j >> 2)][j & 3], b8[2 + (j >> 2)][j & 3]);
      p[1] = cvtpk(b8[4 + (j >> 2)][j & 3], b8[6 + (j >> 2)][j & 3]);
      *(u32x2*)(lbt + (eo + j) * 136 + 4 * cq) = p;
    }
    asm volatile("s_waitcnt lgkmcnt(0)" ::: "memory");
    __builtin_amdgcn_sched_barrier(0);
    __builtin_amdgcn_s_barrier();
    if (kt < 3) {
      pA += 128; pB += (u64)128 * EDIM;
#pragma unroll
      for (int i = 0; i < 8; ++i) a8[i] = *(const f32x4*)(pA + i * 4);
#pragma unroll
      for (int r = 0; r < 4; ++r) {
        b8[r * 2 + 0] = *(const f32x4*)(pB + r * EDIM);
        b8[r * 2 + 1] = *(const f32x4*)(pB + r * EDIM + 4);
      }
    }
#pragma unroll
    for (int kk = 0; kk < 128; kk += 32) {
      bf16x8 a = *(const bf16x8*)(la + (w * 16 + lr) * 136 + kk + lk * 8);
#pragma unroll
      for (int ni = 0; ni < 4; ++ni) {
        bf16x8 bb = *(const bf16x8*)(lbt + (ni * 16 + lr) * 136 + kk + lk * 8);
        acc[ni] = __builtin_amdgcn_mfma_f32_16x16x32_bf16(a, bb, acc[ni], 0, 0, 0);
      }
    }
    asm volatile("s_waitcnt lgkmcnt(0)" ::: "memory");
    __builtin_amdgcn_sched_barrier(0);
    __builtin_amdgcn_s_barrier();
  }
#pragma unroll
  for (int ni = 0; ni < 4; ++ni)
#pragma unroll
    for (int r = 0; r < 4; ++r)
      Mm[(u64)(f0 + w * 16 + lk * 4 + r) * EDIM + e0 + ni * 16 + lr] = f2b(acc[ni][r]);
}

// ---------------------------------------------------------------------------
// conv one K-slice from a 16-row window set into swizzled A-LDS (R11 verified
// numerics). Thread: rows r0..r0+7 (r0 = m0 + tg*8), 4 channels at ct*4.
// ---------------------------------------------------------------------------
template <bool EDGE>
__device__ __forceinline__ void conv_step(const f32x4* W, u16* lds, int abase,
                                          int r0, int tg, int ct, const float* G) {
#pragma unroll
  for (int j = 0; j < 8; ++j) {
    f32x4 o = {};
    int rj = r0 + j;
#pragma unroll
    for (int k = 0; k < 9; ++k) {
      float g = G[k < 4 ? 4 - k : k - 4];
      if (EDGE) g = (((rj + k - 4) >> 12) == (rj >> 12)) ? g : 0.0f;
#pragma unroll
      for (int q = 0; q < 4; ++q) o[q] += g * W[j + k][q];
    }
    int row = tg * 8 + j;
    u32x2 p;
    p[0] = cvtpk(o[0], o[1]);
    p[1] = cvtpk(o[2], o[3]);
    *(u32x2*)(lds + abase + ((row * 64 + ct * 4) ^ ((row & 7) << 3))) = p;
  }
}

// ---------------------------------------------------------------------------
// Fused kernel body. 128x128 tile, BK=64, 8 steps, 4 waves, 64KB LDS
// (A0|A1 8192 u16 each @0/@8192, B0|B1 @16384/@24576), 2 blocks/CU.
// ---------------------------------------------------------------------------
#define FSTEP(KT, WCONS, WISS, VMTOP, VMW)                                     \
  {                                                                            \
    asm volatile("s_waitcnt vmcnt(" #VMTOP ")" ::: "memory");                  \
    __builtin_amdgcn_sched_barrier(0);                                         \
    __builtin_amdgcn_s_barrier();                                              \
    if ((KT) + 1 < 8) {                                                        \
      _Pragma("unroll") for (int i = 0; i < 4; ++i)                            \
          async_cp16(gB + ((KT) + 1) * 64 + (u64)i * 32 * EDIM,                \
                     lds + 16384 + (((KT) + 1) & 1) * 8192 + t * 8 + i * 2048);\
    }                                                                          \
    __builtin_amdgcn_sched_barrier(0);                                         \
    if ((KT) + 2 < 8) {                                                        \
      _Pragma("unroll") for (int i = 0; i < 16; ++i)                           \
          WISS[i] = *(const f32x4*)(in + woff[i] + ((KT) + 2) * 64);           \
    }                                                                          \
    __builtin_amdgcn_sched_barrier(0);                                         \
    {                                                                          \
      const int ab = ((KT) & 1) * 8192, bb = 16384 + ((KT) & 1) * 8192;        \
      _Pragma("unroll") for (int kk = 0; kk < 64; kk += 32) {                  \
        bf16x8 af[4], bv[4];                                                   \
        _Pragma("unroll") for (int mi = 0; mi < 4; ++mi)                       \
            af[mi] = *(const bf16x8*)(lds + ab + ard[mi] +                     \
                                      ((kk + lk * 8) ^ aswz[mi]));             \
        _Pragma("unroll") for (int ni = 0; ni < 4; ++ni)                       \
            bv[ni] = *(const bf16x8*)(lds + bb + brd[ni] +                     \
                                      ((kk + lk * 8) ^ bswz[ni]));             \
        _Pragma("unroll") for (int mi = 0; mi < 4; ++mi)                       \
          _Pragma("unroll") for (int ni = 0; ni < 4; ++ni)                     \
              acc[mi][ni] = __builtin_amdgcn_mfma_f32_16x16x32_bf16(           \
                  af[mi], bv[ni], acc[mi][ni], 0, 0, 0);                       \
      }                                                                        \
    }                                                                          \
    if ((KT) < 7) {                                                            \
      asm volatile("s_waitcnt vmcnt(" #VMW ")" ::: "memory");                  \
      __builtin_amdgcn_sched_barrier(0);                                       \
      conv_step<EDGE>(WCONS, lds, (((KT) + 1) & 1) * 8192, r0, tg, ct, G);     \
      asm volatile("s_waitcnt lgkmcnt(0)" ::: "memory");                       \
      __builtin_amdgcn_sched_barrier(0);                                       \
    }                                                                          \
  }

template <bool EDGE>
__device__ __forceinline__ void fused_body(const float* __restrict__ in,
                                           const u16* __restrict__ Mm,
                                           float* __restrict__ out,
                                           u16* lds, int t, int m0, int n0) {
  const float G[5] = {0.39894228040143270f, 0.24197072451914337f,
                      0.053990966513188063f, 0.0044318484119380075f,
                      1.3383022576488537e-4f};
  int l = t & 63, lr = l & 15, lk = l >> 4;
  int wv = t >> 6, wr = wv >> 1, wc = wv & 1;
  int ct = t & 15, tg = t >> 4;
  int r0 = m0 + tg * 8;

  // window source row offsets (16 rows: r0-4 .. r0+11), clamped under EDGE
  u32 woff[16];
#pragma unroll
  for (int i = 0; i < 16; ++i) {
    int rr = r0 - 4 + i;
    if (EDGE) rr = rr < 0 ? 0 : (rr > NROW - 1 ? NROW - 1 : rr);
    woff[i] = (u32)rr * EDIM + ct * 4;
  }
  int soct = (t & 7) ^ ((t >> 3) & 7);
  const u16* gB = Mm + (u64)(n0 + (t >> 3)) * EDIM + soct * 8;

  int ard[4], aswz[4], brd[4], bswz[4];
#pragma unroll
  for (int mi = 0; mi < 4; ++mi) {
    int rA = wr * 64 + mi * 16 + lr;
    ard[mi] = rA * 64; aswz[mi] = (rA & 7) << 3;
  }
#pragma unroll
  for (int ni = 0; ni < 4; ++ni) {
    int rB = wc * 64 + ni * 16 + lr;
    brd[ni] = rB * 64; bswz[ni] = (rB & 7) << 3;
  }

  f32x4 acc[4][4] = {};
  f32x4 WP[16], WQ[16];

  // ---- prologue: W0 -> P (auto-waited) -> conv -> A0; then B0; then W1 -> Q
#pragma unroll
  for (int i = 0; i < 16; ++i) WP[i] = *(const f32x4*)(in + woff[i]);
  conv_step<EDGE>(WP, lds, 0, r0, tg, ct, G);
  asm volatile("s_waitcnt lgkmcnt(0)" ::: "memory");
  __builtin_amdgcn_sched_barrier(0);
#pragma unroll
  for (int i = 0; i < 4; ++i)
    async_cp16(gB + (u64)i * 32 * EDIM, lds + 16384 + t * 8 + i * 2048);
  __builtin_amdgcn_sched_barrier(0);
#pragma unroll
  for (int i = 0; i < 16; ++i) WQ[i] = *(const f32x4*)(in + woff[i] + 64);
  __builtin_amdgcn_sched_barrier(0);
  // queue now: {B0 x4 (old), W1 x16 (young)}

  FSTEP(0, WQ, WP, 16, 20)
  FSTEP(1, WP, WQ, 16, 20)
  FSTEP(2, WQ, WP, 16, 20)
  FSTEP(3, WP, WQ, 16, 20)
  FSTEP(4, WQ, WP, 16, 20)
  FSTEP(5, WP, WQ, 16, 20)
  FSTEP(6, WQ, WP, 16, 4)
  FSTEP(7, WP, WQ, 0, 0)

  // ---- epilogue: direct fp32 stores from acc
#pragma unroll
  for (int mi = 0; mi < 4; ++mi)
#pragma unroll
    for (int ni = 0; ni < 4; ++ni)
#pragma unroll
      for (int rr = 0; rr < 4; ++rr)
        out[(u64)(m0 + wr * 64 + mi * 16 + lk * 4 + rr) * EDIM +
            n0 + wc * 64 + ni * 16 + lr] = acc[mi][ni][rr];
}

__global__ __launch_bounds__(256, 2) void fused_gc(const float* __restrict__ in,
                                                   const u16* __restrict__ Mm,
                                                   float* __restrict__ out) {
  __shared__ u16 lds[32768];  // 64 KB
  int t = threadIdx.x;
  int b = (int)blockIdx.x;
  int wg = (b & 7) * 64 + (b >> 3);  // bijective XCD swizzle (512 % 8 == 0)
  int m0 = (wg >> 2) * 128;
  int n0 = (wg & 3) * 128;
  bool edge = (((m0 - 4) >> 12) != ((m0 + 131) >> 12));
  if (edge)
    fused_body<true>(in, Mm, out, lds, t, m0, n0);
  else
    fused_body<false>(in, Mm, out, lds, t, m0, n0);
}

extern "C" void kernel_launch(void* const* d_in, const int* in_sizes, int n_in,
                              void* d_out, int out_size, void* d_ws, size_t ws_size,
                              hipStream_t stream) {
  const float* in   = (const float*)d_in[0];  // [4,4096,512] f32
  const float* Win  = (const float*)d_in[1];  // [512,512] f32
  const float* Wout = (const float*)d_in[2];  // [512,512] f32
  float* outp = (float*)d_out;                // [4,4096,512] f32

  u16* Mm = (u16*)d_ws;                       // 512*512 bf16

  hipLaunchKernelGGL(gemm_m,   dim3(64),  dim3(256), 0, stream, Wout, Win, Mm);
  hipLaunchKernelGGL(fused_gc, dim3(512), dim3(256), 0, stream, in, Mm, outp);
}